// Round 9
// baseline (159.614 us; speedup 1.0000x reference)
//
#include <hip/hip_runtime.h>

// ---------------------------------------------------------------------------
// AveragedKeyCircularConvolutionalAttention  (B=2, N=2048, C=768, h=12, d=64)
// R9: K-loops rewritten as triple-buffered, fine-vmcnt pipelines
// (raw s_barrier, s_waitcnt vmcnt(S) -- prefetch stays in flight across the
// barrier; the AITER/hipBLASLt pattern). R8 measured k_mid at 51us with
// MfmaUtil 3% -- the __syncthreads vmcnt(0) drain was fully exposed at
// ~1 block/CU.
//
//  N1 k_prep : x,Wv,Wp -> bf16 ; blocks 0..63 write colsum partials x_part
//  N2 k_mid  : blocks 0..191  VT = (x@Wv^T)^T  (BK=64, 3-buf pipeline)
//              blocks 192..287 ubz: x_avg -> K_avg -> u (fp32) -> z_t (VALU)
//  N3 k_conv : in-block softmax(z_t) + circulant MFMA -> out_pre (384 blk)
//  N4 k_out  : out = out_pre @ Wp^T + bp  (f32)                  (192 blk)
// ---------------------------------------------------------------------------

typedef __bf16 bf16x8 __attribute__((ext_vector_type(8)));
typedef float  f32x4  __attribute__((ext_vector_type(4)));

#define AS_GLOBAL(p) ((const __attribute__((address_space(1))) unsigned int*)(p))
#define AS_LDS(p)    ((__attribute__((address_space(3))) unsigned int*)(p))

__device__ __forceinline__ void async16(const void* g, void* l) {
    __builtin_amdgcn_global_load_lds(AS_GLOBAL(g), AS_LDS(l), 16, 0, 0);
}

#define WAITVM(N) asm volatile("s_waitcnt vmcnt(" #N ")" ::: "memory")
#define RAW_BARRIER() asm volatile("s_barrier" ::: "memory")

struct bf4 { __bf16 a, b, c, d; };

// ---------------------------------------------------------------------------
// Pipelined bf16 GEMM tile: C[m][n] = sum_k A[m][k]*Bt[n][k].
// BM=BN=128, BK=64, triple-buffered (3 x 32KB LDS), S=8 loads/thread/stage.
// Steady state: wait vmcnt(8) -> only the stage being consumed is drained;
// the next stage's 8 loads remain in flight across the raw s_barrier.
// MODE 0: bf16 store   MODE 1: f32 + bias
// ---------------------------------------------------------------------------
template <int MODE>
__device__ void gemm_phase(char* smem, const __bf16* __restrict__ A,
                           const __bf16* __restrict__ Bt, void* __restrict__ Cout,
                           const float* __restrict__ bias,
                           int K, int ldA, int ldBt, int ldC, int mBase, int nBase)
{
    constexpr int BM = 128, BN = 128, BK = 64;
    constexpr int BUF = (BM + BN) * BK * 2;       // 32768 B per buffer
    const int tid = threadIdx.x;
    const int lane = tid & 63, wid = tid >> 6;
    const int lane15 = lane & 15, quad = lane >> 4;
    const int wm = (wid & 1) * 64, wn = (wid >> 1) * 64;

    auto stage = [&](int kb, char* buf) {
        __bf16* As = (__bf16*)buf;
        __bf16* Bs = As + BM * BK;
#pragma unroll
        for (int c0 = 0; c0 < BM * 8; c0 += 256) {
            int c = c0 + tid, row = c >> 3, slot = c & 7;
            int k8 = slot ^ (row & 7);
            async16(A + (size_t)(mBase + row) * ldA + kb + k8 * 8, As + c * 8);
        }
#pragma unroll
        for (int c0 = 0; c0 < BN * 8; c0 += 256) {
            int c = c0 + tid, row = c >> 3, slot = c & 7;
            int k8 = slot ^ (row & 7);
            async16(Bt + (size_t)(nBase + row) * ldBt + kb + k8 * 8, Bs + c * 8);
        }
    };

    f32x4 acc[4][4] = {};
    const int nk = K >> 6;                        // 12
    char* p0 = smem;
    char* p1 = smem + BUF;
    char* p2 = smem + 2 * BUF;

    stage(0, p0);
    stage(64, p1);
    for (int ki = 0; ki < nk; ++ki) {
        if (ki + 1 < nk) { WAITVM(8); } else { WAITVM(0); }
        RAW_BARRIER();                            // no drain of newer stage
        if (ki + 2 < nk) stage((ki + 2) << 6, p2);

        __bf16* As = (__bf16*)p0;
        __bf16* Bs = As + BM * BK;
#pragma unroll
        for (int ks = 0; ks < 2; ++ks) {
            bf16x8 af[4], bv[4];
#pragma unroll
            for (int mi = 0; mi < 4; ++mi) {
                int row = wm + mi * 16 + lane15;
                af[mi] = *(const bf16x8*)&As[row * 64 + ((ks * 4 + quad) ^ (row & 7)) * 8];
            }
#pragma unroll
            for (int ni = 0; ni < 4; ++ni) {
                int row = wn + ni * 16 + lane15;
                bv[ni] = *(const bf16x8*)&Bs[row * 64 + ((ks * 4 + quad) ^ (row & 7)) * 8];
            }
#pragma unroll
            for (int mi = 0; mi < 4; ++mi)
#pragma unroll
                for (int ni = 0; ni < 4; ++ni)
                    acc[mi][ni] = __builtin_amdgcn_mfma_f32_16x16x32_bf16(
                        af[mi], bv[ni], acc[mi][ni], 0, 0, 0);
        }
        char* t = p0; p0 = p1; p1 = p2; p2 = t;
    }

#pragma unroll
    for (int mi = 0; mi < 4; ++mi)
#pragma unroll
        for (int ni = 0; ni < 4; ++ni)
#pragma unroll
            for (int r = 0; r < 4; ++r) {
                int row = mBase + wm + mi * 16 + quad * 4 + r;
                int col = nBase + wn + ni * 16 + lane15;
                float v = acc[mi][ni][r];
                if (MODE == 0) {
                    ((__bf16*)Cout)[(size_t)row * ldC + col] = (__bf16)v;
                } else {
                    ((float*)Cout)[(size_t)row * ldC + col] = v + bias[col];
                }
            }
}

// ---------------------------------------------------------------------------
// N1: converts; blocks 0..63 also write column-sum partials over 64-row
// groups: x_part[g][c] = sum_{r in [g*64,g*64+64)} x[r][c]
// ---------------------------------------------------------------------------
__global__ __launch_bounds__(256)
void k_prep(const float* __restrict__ x, const float* __restrict__ Wv,
            const float* __restrict__ Wp,
            __bf16* __restrict__ xb, __bf16* __restrict__ Wvb,
            __bf16* __restrict__ Wpb, float* __restrict__ x_part)
{
    const int bid = blockIdx.x, tid = threadIdx.x;

    const float4* xs = (const float4*)x + (size_t)bid * 1536;  // 8 rows
    bf4* xd = (bf4*)xb + (size_t)bid * 1536;
#pragma unroll
    for (int r = 0; r < 6; ++r) {
        int j = tid + r * 256;          // < 1536
        float4 v = xs[j];
        xd[j] = bf4{(__bf16)v.x, (__bf16)v.y, (__bf16)v.z, (__bf16)v.w};
    }
    const float4* wv4 = (const float4*)Wv;  bf4* wvb4 = (bf4*)Wvb;
    const float4* wp4 = (const float4*)Wp;  bf4* wpb4 = (bf4*)Wpb;
    for (int t = tid; t < 288; t += 256) {
        int g = bid * 288 + t;
        float4 v = wv4[g];
        wvb4[g] = bf4{(__bf16)v.x, (__bf16)v.y, (__bf16)v.z, (__bf16)v.w};
        float4 w2 = wp4[g];
        wpb4[g] = bf4{(__bf16)w2.x, (__bf16)w2.y, (__bf16)w2.z, (__bf16)w2.w};
    }

    if (bid < 64) {  // colsum of rows [bid*64, bid*64+64)
        const float* base = x + (size_t)bid * 64 * 768;
        float s0 = 0.f, s1 = 0.f, s2 = 0.f;
        for (int r = 0; r < 64; ++r) {
            const float* row = base + r * 768;
            s0 += row[tid];
            s1 += row[tid + 256];
            s2 += row[tid + 512];
        }
        x_part[bid * 768 + tid]       = s0;
        x_part[bid * 768 + tid + 256] = s1;
        x_part[bid * 768 + tid + 512] = s2;
    }
}

// ---------------------------------------------------------------------------
// N2: blocks 0..191 VT gemm (pipelined);  blocks 192..287 ubz (4 per bh,
// each a 512-token quarter): x_avg -> K_avg -> u (fp32) -> z_t quarter
// ---------------------------------------------------------------------------
__global__ __launch_bounds__(256, 2)
void k_mid(const __bf16* __restrict__ xb, const __bf16* __restrict__ Wvb,
           const float* __restrict__ x_part, const float* __restrict__ Wk,
           const float* __restrict__ Wq,
           __bf16* __restrict__ VT, float* __restrict__ z_t)
{
    __shared__ __attribute__((aligned(16))) char smem[98304];
    const int bid = blockIdx.x;
    if (bid < 192) {
        gemm_phase<0>(smem, Wvb, xb, VT, nullptr, 768, 768, 768, 4096,
                      (bid / 32) * 128, (bid % 32) * 128);
        return;
    }
    const int tid = threadIdx.x;
    const int lane = tid & 63, wid = tid >> 6;
    const int idx = bid - 192;                 // 0..95
    const int bh = idx >> 2, q = idx & 3;
    const int b = bh / 12, h = bh % 12;
    float* xa  = (float*)smem;                 // 768
    float* uld = xa + 768;                     // 768
    float* ka  = uld + 768;                    // 64

    for (int c = tid; c < 768; c += 256) {
        float s = 0.f;
#pragma unroll
        for (int g = 0; g < 32; ++g) s += x_part[(b * 32 + g) * 768 + c];
        xa[c] = s;
    }
    __syncthreads();
    for (int round = 0; round < 16; ++round) {  // K_avg, wave-per-row
        int o = round * 4 + wid;
        const float* wk = Wk + (size_t)(h * 64 + o) * 768;
        float s = 0.f;
#pragma unroll
        for (int c0 = 0; c0 < 768; c0 += 64) s += xa[c0 + lane] * wk[c0 + lane];
#pragma unroll
        for (int off = 32; off; off >>= 1) s += __shfl_down(s, off);
        if (lane == 0) ka[o] = s * (0.125f / 2048.f);  // fold SCALE and 1/N
    }
    __syncthreads();
    for (int c = tid; c < 768; c += 256) {      // u row (fp32)
        float s = 0.f;
#pragma unroll 16
        for (int d = 0; d < 64; ++d)
            s += ka[d] * Wq[(size_t)(h * 64 + d) * 768 + c];
        uld[c] = s;
    }
    __syncthreads();
    const int t0 = q * 512 + tid, t1 = t0 + 256;
    const bf16x8* r0 = (const bf16x8*)(xb + (size_t)(b * 2048 + t0) * 768);
    const bf16x8* r1 = (const bf16x8*)(xb + (size_t)(b * 2048 + t1) * 768);
    const float4* u4 = (const float4*)uld;
    float s0 = 0.f, s1 = 0.f;
#pragma unroll 8
    for (int j = 0; j < 96; ++j) {
        bf16x8 v0 = r0[j], v1 = r1[j];
        float4 ua = u4[j * 2], ub = u4[j * 2 + 1];
        s0 += (float)v0[0] * ua.x + (float)v0[1] * ua.y + (float)v0[2] * ua.z
            + (float)v0[3] * ua.w + (float)v0[4] * ub.x + (float)v0[5] * ub.y
            + (float)v0[6] * ub.z + (float)v0[7] * ub.w;
        s1 += (float)v1[0] * ua.x + (float)v1[1] * ua.y + (float)v1[2] * ua.z
            + (float)v1[3] * ua.w + (float)v1[4] * ub.x + (float)v1[5] * ub.y
            + (float)v1[6] * ub.z + (float)v1[7] * ub.w;
    }
    z_t[(size_t)bh * 2048 + t0] = s0;
    z_t[(size_t)bh * 2048 + t1] = s1;
}

// ---------------------------------------------------------------------------
// N3: conv, 384 blocks: 16 tiles of 128 rows x 64 dd per (b,h).
// K-chunk 64, triple-buffered pipeline (S=2 loads/thread/stage).
// smem: rep[8][2056] @0 (32896) | attn_s @32896 (4096) |
//       vt0/1/2 @36992 (3 x 8192)    total 61568 -> 2 blocks/CU
// ---------------------------------------------------------------------------
__global__ __launch_bounds__(256, 2)
void k_conv(const float* __restrict__ z_t, const __bf16* __restrict__ VT,
            __bf16* __restrict__ outp)
{
    __shared__ __attribute__((aligned(16))) char smem[61568];
    __bf16 (*rep)[2056] = (__bf16(*)[2056])smem;
    __bf16* attn_s = (__bf16*)(smem + 32896);
    float* red = (float*)(smem + 36992);       // aliases vt area (pre-stage)

    const int bid = blockIdx.x, tid = threadIdx.x;
    const int lane = tid & 63, wid = tid >> 6;
    const int lane15 = lane & 15, quad = lane >> 4;
    const int bh = bid >> 4, b = bh / 12, h = bh % 12;
    const int m0 = (bid & 15) * 128 + (wid & 1) * 64;
    const int wn = (wid >> 1) * 32;

    // softmax of z_t row -> attn_s (attn/N, bf16)
    {
        const float* z = z_t + (size_t)bh * 2048;
        float v[8];
        float m = -1e30f;
#pragma unroll
        for (int j = 0; j < 8; ++j) { v[j] = z[tid + j * 256]; m = fmaxf(m, v[j]); }
#pragma unroll
        for (int off = 32; off; off >>= 1) m = fmaxf(m, __shfl_xor(m, off));
        if (lane == 0) red[wid] = m;
        __syncthreads();
        m = fmaxf(fmaxf(red[0], red[1]), fmaxf(red[2], red[3]));
        __syncthreads();
        float s = 0.f;
#pragma unroll
        for (int j = 0; j < 8; ++j) { v[j] = __expf(v[j] - m); s += v[j]; }
#pragma unroll
        for (int off = 32; off; off >>= 1) s += __shfl_xor(s, off);
        if (lane == 0) red[wid] = s;
        __syncthreads();
        s = red[0] + red[1] + red[2] + red[3];
        float inv = 1.f / (s * 2048.f);
#pragma unroll
        for (int j = 0; j < 8; ++j)
            attn_s[tid + j * 256] = (__bf16)(v[j] * inv);
    }
    __syncthreads();
    for (int idx = tid; idx < 8 * 2048; idx += 256) {
        int a = idx >> 11, u = idx & 2047;
        rep[a][u] = attn_s[(u + a) & 2047];
    }
    __syncthreads();                            // rep ready for all waves

    const __bf16* vsrc = VT + (size_t)h * 64 * 4096 + b * 2048;

    auto stage = [&](int kb, char* buf) {       // 64 dd x 64 k tile
        __bf16* vt = (__bf16*)buf;
#pragma unroll
        for (int c0 = 0; c0 < 512; c0 += 256) {
            int c = c0 + tid, dd = c >> 3, slot = c & 7;
            int k8 = slot ^ (dd & 7);
            async16(vsrc + (size_t)dd * 4096 + kb * 64 + k8 * 8, vt + c * 8);
        }
    };

    f32x4 acc[4][2] = {};
    char* p0 = smem + 36992;
    char* p1 = p0 + 8192;
    char* p2 = p1 + 8192;
    stage(0, p0);
    stage(1, p1);
    for (int kb = 0; kb < 32; ++kb) {
        if (kb + 1 < 32) { WAITVM(2); } else { WAITVM(0); }
        RAW_BARRIER();
        if (kb + 2 < 32) stage(kb + 2, p2);
        __bf16* vt = (__bf16*)p0;

#pragma unroll
        for (int ks = 0; ks < 2; ++ks) {
            int kloc = ks * 32 + quad * 8;
            int kglob = kb * 64 + kloc;
            bf16x8 af[4], bv[2];
#pragma unroll
            for (int mi = 0; mi < 4; ++mi) {
                int m = m0 + mi * 16 + lane15;
                int p = (kglob - m) & 2047;
                int al = p & 7;
                af[mi] = *(const bf16x8*)&rep[al][p - al];
            }
#pragma unroll
            for (int ni = 0; ni < 2; ++ni) {
                int dd = wn + ni * 16 + lane15;
                int slot = (ks * 4 + quad) ^ (dd & 7);
                bv[ni] = *(const bf16x8*)&vt[dd * 64 + slot * 8];
            }
#pragma unroll
            for (int mi = 0; mi < 4; ++mi)
#pragma unroll
                for (int ni = 0; ni < 2; ++ni)
                    acc[mi][ni] = __builtin_amdgcn_mfma_f32_16x16x32_bf16(
                        af[mi], bv[ni], acc[mi][ni], 0, 0, 0);
        }
        char* t = p0; p0 = p1; p1 = p2; p2 = t;
    }

#pragma unroll
    for (int mi = 0; mi < 4; ++mi)
#pragma unroll
        for (int ni = 0; ni < 2; ++ni)
#pragma unroll
            for (int r = 0; r < 4; ++r) {
                int i = m0 + mi * 16 + quad * 4 + r;
                int dd = wn + ni * 16 + lane15;
                outp[(size_t)(b * 2048 + i) * 768 + h * 64 + dd] =
                    (__bf16)acc[mi][ni][r];
            }
}

// ---------------------------------------------------------------------------
// N4: out = out_pre @ Wp^T + bp  (f32)
// ---------------------------------------------------------------------------
__global__ __launch_bounds__(256, 2)
void k_out(const __bf16* __restrict__ out_pre, const __bf16* __restrict__ Wpb,
           const float* __restrict__ bp, float* __restrict__ out)
{
    __shared__ __attribute__((aligned(16))) char smem[98304];
    const int bid = blockIdx.x;
    gemm_phase<1>(smem, out_pre, Wpb, out, bp, 768, 768, 768, 768,
                  (bid / 6) * 128, (bid % 6) * 128);
}

// ---------------------------------------------------------------------------
extern "C" void kernel_launch(void* const* d_in, const int* in_sizes, int n_in,
                              void* d_out, int out_size, void* d_ws, size_t ws_size,
                              hipStream_t stream)
{
    (void)in_sizes; (void)n_in; (void)out_size; (void)ws_size;
    const float* x  = (const float*)d_in[0];
    const float* Wq = (const float*)d_in[1];
    const float* Wk = (const float*)d_in[2];
    const float* Wv = (const float*)d_in[3];
    const float* Wp = (const float*)d_in[4];
    const float* bp = (const float*)d_in[5];

    char* w = (char*)d_ws;
    auto alloc = [&](size_t bytes) {
        char* p = w; w += (bytes + 255) & ~(size_t)255; return p;
    };
    float*  x_part  = (float*) alloc((size_t)64 * 768 * 4);
    __bf16* xb      = (__bf16*)alloc((size_t)4096 * 768 * 2);
    __bf16* Wvb     = (__bf16*)alloc((size_t)768 * 768 * 2);
    __bf16* Wpb     = (__bf16*)alloc((size_t)768 * 768 * 2);
    float*  z_t     = (float*) alloc((size_t)24 * 2048 * 4);
    __bf16* VT      = (__bf16*)alloc((size_t)768 * 4096 * 2);
    __bf16* out_pre = (__bf16*)alloc((size_t)4096 * 768 * 2);

    k_prep<<<512, 256, 0, stream>>>(x, Wv, Wp, xb, Wvb, Wpb, x_part);
    k_mid <<<288, 256, 0, stream>>>(xb, Wvb, x_part, Wk, Wq, VT, z_t);
    k_conv<<<384, 256, 0, stream>>>(z_t, VT, out_pre);
    k_out <<<192, 256, 0, stream>>>(out_pre, Wpb, bp, (float*)d_out);
}

// Round 10
// 139.943 us; speedup vs baseline: 1.1406x; 1.1406x over previous
//
#include <hip/hip_runtime.h>

// ---------------------------------------------------------------------------
// AveragedKeyCircularConvolutionalAttention  (B=2, N=2048, C=768, h=12, d=64)
// R10: split R9's k_mid (GEMM + serial ubz in one dispatch, 51us, blind
// attribution) into k_ub (96 blk, parallel averaged-key path -> Ub) and
// k_mid (pure MFMA: 192 VT + 32 z-gemm, R9 3-buf fine-vmcnt pipeline).
//
//  N1 k_prep : x,Wv,Wp -> bf16 ; blocks 0..63 colsum partials x_part
//  N2 k_ub   : 4 blk/bh: x_avg -> K_avg -> u quarter -> Ub bf16   (96 blk)
//  N3 k_mid  : VT = (x@Wv^T)^T (192) || z_t = (xb@Ub^T)^T (32)    (224 blk)
//  N4 k_conv : in-block softmax(z_t) + circulant MFMA -> out_pre  (384 blk)
//  N5 k_out  : out = out_pre @ Wp^T + bp  (f32)                   (192 blk)
// ---------------------------------------------------------------------------

typedef __bf16 bf16x8 __attribute__((ext_vector_type(8)));
typedef float  f32x4  __attribute__((ext_vector_type(4)));

#define AS_GLOBAL(p) ((const __attribute__((address_space(1))) unsigned int*)(p))
#define AS_LDS(p)    ((__attribute__((address_space(3))) unsigned int*)(p))

__device__ __forceinline__ void async16(const void* g, void* l) {
    __builtin_amdgcn_global_load_lds(AS_GLOBAL(g), AS_LDS(l), 16, 0, 0);
}

#define WAITVM(N) asm volatile("s_waitcnt vmcnt(" #N ")" ::: "memory")
#define RAW_BARRIER() asm volatile("s_barrier" ::: "memory")

struct bf4 { __bf16 a, b, c, d; };

// ---------------------------------------------------------------------------
// Pipelined bf16 GEMM tile: C[m][n] = sum_k A[m][k]*Bt[n][k].
// BM=128, BK=64, triple-buffered, fine vmcnt (prefetch crosses the barrier).
// BN=128: 4 waves x 64x64, 8 loads/thread/stage -> steady WAITVM(8)
// BN= 32: 4 waves x 64x16, 5 loads/thread/stage -> steady WAITVM(5)
// MODE 0: bf16 store   MODE 1: f32 + bias   MODE 2: z transposed f32
// ---------------------------------------------------------------------------
template <int BN, int MODE>
__device__ void gemm_phase(char* smem, const __bf16* __restrict__ A,
                           const __bf16* __restrict__ Bt, void* __restrict__ Cout,
                           const float* __restrict__ bias,
                           int K, int ldA, int ldBt, int ldC, int mBase, int nBase)
{
    constexpr int BM = 128, BK = 64;
    constexpr int BUF = (BM + BN) * BK * 2;
    constexpr int WN = BN / 2, NI = WN / 16;
    const int tid = threadIdx.x;
    const int lane = tid & 63, wid = tid >> 6;
    const int lane15 = lane & 15, quad = lane >> 4;
    const int wm = (wid & 1) * 64, wn = (wid >> 1) * WN;

    auto stage = [&](int kb, char* buf) {
        __bf16* As = (__bf16*)buf;
        __bf16* Bs = As + BM * BK;
#pragma unroll
        for (int c0 = 0; c0 < BM * 8; c0 += 256) {
            int c = c0 + tid, row = c >> 3, slot = c & 7;
            int k8 = slot ^ (row & 7);
            async16(A + (size_t)(mBase + row) * ldA + kb + k8 * 8, As + c * 8);
        }
#pragma unroll
        for (int c0 = 0; c0 < BN * 8; c0 += 256) {
            int c = c0 + tid, row = c >> 3, slot = c & 7;
            int k8 = slot ^ (row & 7);
            async16(Bt + (size_t)(nBase + row) * ldBt + kb + k8 * 8, Bs + c * 8);
        }
    };

    f32x4 acc[4][NI] = {};
    const int nk = K >> 6;                        // 12
    char* p0 = smem;
    char* p1 = smem + BUF;
    char* p2 = smem + 2 * BUF;

    stage(0, p0);
    stage(64, p1);
    for (int ki = 0; ki < nk; ++ki) {
        if (ki + 1 < nk) {
            if constexpr (BN == 128) { WAITVM(8); } else { WAITVM(5); }
        } else { WAITVM(0); }
        RAW_BARRIER();                            // newer stage stays in flight
        if (ki + 2 < nk) stage((ki + 2) << 6, p2);

        __bf16* As = (__bf16*)p0;
        __bf16* Bs = As + BM * BK;
#pragma unroll
        for (int ks = 0; ks < 2; ++ks) {
            bf16x8 af[4], bv[NI];
#pragma unroll
            for (int mi = 0; mi < 4; ++mi) {
                int row = wm + mi * 16 + lane15;
                af[mi] = *(const bf16x8*)&As[row * 64 + ((ks * 4 + quad) ^ (row & 7)) * 8];
            }
#pragma unroll
            for (int ni = 0; ni < NI; ++ni) {
                int row = wn + ni * 16 + lane15;
                bv[ni] = *(const bf16x8*)&Bs[row * 64 + ((ks * 4 + quad) ^ (row & 7)) * 8];
            }
#pragma unroll
            for (int mi = 0; mi < 4; ++mi)
#pragma unroll
                for (int ni = 0; ni < NI; ++ni)
                    acc[mi][ni] = __builtin_amdgcn_mfma_f32_16x16x32_bf16(
                        af[mi], bv[ni], acc[mi][ni], 0, 0, 0);
        }
        char* t = p0; p0 = p1; p1 = p2; p2 = t;
    }

#pragma unroll
    for (int mi = 0; mi < 4; ++mi)
#pragma unroll
        for (int ni = 0; ni < NI; ++ni)
#pragma unroll
            for (int r = 0; r < 4; ++r) {
                int row = mBase + wm + mi * 16 + quad * 4 + r;
                int col = nBase + wn + ni * 16 + lane15;
                float v = acc[mi][ni][r];
                if (MODE == 0) {
                    ((__bf16*)Cout)[(size_t)row * ldC + col] = (__bf16)v;
                } else if (MODE == 1) {
                    ((float*)Cout)[(size_t)row * ldC + col] = v + bias[col];
                } else {
                    int b = row >> 11;
                    if ((unsigned)(col - b * 12) < 12u)
                        ((float*)Cout)[(size_t)col * 2048 + (row & 2047)] = v;
                }
            }
}

// ---------------------------------------------------------------------------
// N1: converts; blocks 0..63 also write colsum partials over 64-row groups
// ---------------------------------------------------------------------------
__global__ __launch_bounds__(256)
void k_prep(const float* __restrict__ x, const float* __restrict__ Wv,
            const float* __restrict__ Wp,
            __bf16* __restrict__ xb, __bf16* __restrict__ Wvb,
            __bf16* __restrict__ Wpb, float* __restrict__ x_part)
{
    const int bid = blockIdx.x, tid = threadIdx.x;

    const float4* xs = (const float4*)x + (size_t)bid * 1536;  // 8 rows
    bf4* xd = (bf4*)xb + (size_t)bid * 1536;
#pragma unroll
    for (int r = 0; r < 6; ++r) {
        int j = tid + r * 256;          // < 1536
        float4 v = xs[j];
        xd[j] = bf4{(__bf16)v.x, (__bf16)v.y, (__bf16)v.z, (__bf16)v.w};
    }
    const float4* wv4 = (const float4*)Wv;  bf4* wvb4 = (bf4*)Wvb;
    const float4* wp4 = (const float4*)Wp;  bf4* wpb4 = (bf4*)Wpb;
    for (int t = tid; t < 288; t += 256) {
        int g = bid * 288 + t;
        float4 v = wv4[g];
        wvb4[g] = bf4{(__bf16)v.x, (__bf16)v.y, (__bf16)v.z, (__bf16)v.w};
        float4 w2 = wp4[g];
        wpb4[g] = bf4{(__bf16)w2.x, (__bf16)w2.y, (__bf16)w2.z, (__bf16)w2.w};
    }

    if (bid < 64) {  // colsum of rows [bid*64, bid*64+64)
        const float* base = x + (size_t)bid * 64 * 768;
        float s0 = 0.f, s1 = 0.f, s2 = 0.f;
        for (int r = 0; r < 64; ++r) {
            const float* row = base + r * 768;
            s0 += row[tid];
            s1 += row[tid + 256];
            s2 += row[tid + 512];
        }
        x_part[bid * 768 + tid]       = s0;
        x_part[bid * 768 + tid + 256] = s1;
        x_part[bid * 768 + tid + 512] = s2;
    }
}

// ---------------------------------------------------------------------------
// N2: k_ub, 96 blocks (4 per bh, quarter q of the u row each):
//   x_avg (from x_part, LDS) -> K_avg h-slice (wave-per-row, x4 redundant)
//   -> u[c] for c in [q*192, q*192+192) -> Ub bf16.
// Ub rows 24..31 stay ws-poison (finite); z-gemm bound check discards them.
// ---------------------------------------------------------------------------
__global__ __launch_bounds__(256)
void k_ub(const float* __restrict__ x_part, const float* __restrict__ Wk,
          const float* __restrict__ Wq, __bf16* __restrict__ Ub)
{
    const int bid = blockIdx.x, tid = threadIdx.x;
    const int lane = tid & 63, wid = tid >> 6;
    const int bh = bid >> 2, q = bid & 3;
    const int b = bh / 12, h = bh % 12;
    __shared__ float xa[768];
    __shared__ float ka[64];

    for (int c = tid; c < 768; c += 256) {
        float s = 0.f;
#pragma unroll
        for (int g = 0; g < 32; ++g) s += x_part[(b * 32 + g) * 768 + c];
        xa[c] = s;
    }
    __syncthreads();
    for (int round = 0; round < 16; ++round) {  // K_avg, wave-per-row
        int o = round * 4 + wid;
        const float* wk = Wk + (size_t)(h * 64 + o) * 768;
        float s = 0.f;
#pragma unroll
        for (int c0 = 0; c0 < 768; c0 += 64) s += xa[c0 + lane] * wk[c0 + lane];
#pragma unroll
        for (int off = 32; off; off >>= 1) s += __shfl_down(s, off);
        if (lane == 0) ka[o] = s * (0.125f / 2048.f);  // fold SCALE and 1/N
    }
    __syncthreads();
    if (tid < 192) {                            // u quarter, coalesced in c
        int c = q * 192 + tid;
        float s = 0.f;
#pragma unroll 16
        for (int d = 0; d < 64; ++d)
            s += ka[d] * Wq[(size_t)(h * 64 + d) * 768 + c];
        Ub[(size_t)bh * 768 + c] = (__bf16)s;
    }
}

// ---------------------------------------------------------------------------
// N3: pure MFMA: blocks 0..191 VT gemm; 192..223 z gemm (BN=32)
// ---------------------------------------------------------------------------
__global__ __launch_bounds__(256, 2)
void k_mid(const __bf16* __restrict__ xb, const __bf16* __restrict__ Wvb,
           const __bf16* __restrict__ Ub,
           __bf16* __restrict__ VT, float* __restrict__ z_t)
{
    __shared__ __attribute__((aligned(16))) char smem[98304];
    const int bid = blockIdx.x;
    if (bid < 192) {
        gemm_phase<128, 0>(smem, Wvb, xb, VT, nullptr, 768, 768, 768, 4096,
                           (bid / 32) * 128, (bid % 32) * 128);
    } else {
        gemm_phase<32, 2>(smem, xb, Ub, z_t, nullptr, 768, 768, 768, 0,
                          (bid - 192) * 128, 0);
    }
}

// ---------------------------------------------------------------------------
// N4: conv, 384 blocks: 16 tiles of 128 rows x 64 dd per (b,h).
// K-chunk 64, triple-buffered fine-vmcnt pipeline.
// smem: rep[8][2056] @0 (32896) | attn_s @32896 (4096) |
//       vt0/1/2 @36992 (3 x 8192)    total 61568
// ---------------------------------------------------------------------------
__global__ __launch_bounds__(256, 2)
void k_conv(const float* __restrict__ z_t, const __bf16* __restrict__ VT,
            __bf16* __restrict__ outp)
{
    __shared__ __attribute__((aligned(16))) char smem[61568];
    __bf16 (*rep)[2056] = (__bf16(*)[2056])smem;
    __bf16* attn_s = (__bf16*)(smem + 32896);
    float* red = (float*)(smem + 36992);       // aliases vt area (pre-stage)

    const int bid = blockIdx.x, tid = threadIdx.x;
    const int lane = tid & 63, wid = tid >> 6;
    const int lane15 = lane & 15, quad = lane >> 4;
    const int bh = bid >> 4, b = bh / 12, h = bh % 12;
    const int m0 = (bid & 15) * 128 + (wid & 1) * 64;
    const int wn = (wid >> 1) * 32;

    // softmax of z_t row -> attn_s (attn/N, bf16)
    {
        const float* z = z_t + (size_t)bh * 2048;
        float v[8];
        float m = -1e30f;
#pragma unroll
        for (int j = 0; j < 8; ++j) { v[j] = z[tid + j * 256]; m = fmaxf(m, v[j]); }
#pragma unroll
        for (int off = 32; off; off >>= 1) m = fmaxf(m, __shfl_xor(m, off));
        if (lane == 0) red[wid] = m;
        __syncthreads();
        m = fmaxf(fmaxf(red[0], red[1]), fmaxf(red[2], red[3]));
        __syncthreads();
        float s = 0.f;
#pragma unroll
        for (int j = 0; j < 8; ++j) { v[j] = __expf(v[j] - m); s += v[j]; }
#pragma unroll
        for (int off = 32; off; off >>= 1) s += __shfl_xor(s, off);
        if (lane == 0) red[wid] = s;
        __syncthreads();
        s = red[0] + red[1] + red[2] + red[3];
        float inv = 1.f / (s * 2048.f);
#pragma unroll
        for (int j = 0; j < 8; ++j)
            attn_s[tid + j * 256] = (__bf16)(v[j] * inv);
    }
    __syncthreads();
    for (int idx = tid; idx < 8 * 2048; idx += 256) {
        int a = idx >> 11, u = idx & 2047;
        rep[a][u] = attn_s[(u + a) & 2047];
    }
    __syncthreads();                            // rep ready for all waves

    const __bf16* vsrc = VT + (size_t)h * 64 * 4096 + b * 2048;

    auto stage = [&](int kb, char* buf) {       // 64 dd x 64 k tile
        __bf16* vt = (__bf16*)buf;
#pragma unroll
        for (int c0 = 0; c0 < 512; c0 += 256) {
            int c = c0 + tid, dd = c >> 3, slot = c & 7;
            int k8 = slot ^ (dd & 7);
            async16(vsrc + (size_t)dd * 4096 + kb * 64 + k8 * 8, vt + c * 8);
        }
    };

    f32x4 acc[4][2] = {};
    char* p0 = smem + 36992;
    char* p1 = p0 + 8192;
    char* p2 = p1 + 8192;
    stage(0, p0);
    stage(1, p1);
    for (int kb = 0; kb < 32; ++kb) {
        if (kb + 1 < 32) { WAITVM(2); } else { WAITVM(0); }
        RAW_BARRIER();
        if (kb + 2 < 32) stage(kb + 2, p2);
        __bf16* vt = (__bf16*)p0;

#pragma unroll
        for (int ks = 0; ks < 2; ++ks) {
            int kloc = ks * 32 + quad * 8;
            int kglob = kb * 64 + kloc;
            bf16x8 af[4], bv[2];
#pragma unroll
            for (int mi = 0; mi < 4; ++mi) {
                int m = m0 + mi * 16 + lane15;
                int p = (kglob - m) & 2047;
                int al = p & 7;
                af[mi] = *(const bf16x8*)&rep[al][p - al];
            }
#pragma unroll
            for (int ni = 0; ni < 2; ++ni) {
                int dd = wn + ni * 16 + lane15;
                int slot = (ks * 4 + quad) ^ (dd & 7);
                bv[ni] = *(const bf16x8*)&vt[dd * 64 + slot * 8];
            }
#pragma unroll
            for (int mi = 0; mi < 4; ++mi)
#pragma unroll
                for (int ni = 0; ni < 2; ++ni)
                    acc[mi][ni] = __builtin_amdgcn_mfma_f32_16x16x32_bf16(
                        af[mi], bv[ni], acc[mi][ni], 0, 0, 0);
        }
        char* t = p0; p0 = p1; p1 = p2; p2 = t;
    }

#pragma unroll
    for (int mi = 0; mi < 4; ++mi)
#pragma unroll
        for (int ni = 0; ni < 2; ++ni)
#pragma unroll
            for (int r = 0; r < 4; ++r) {
                int i = m0 + mi * 16 + quad * 4 + r;
                int dd = wn + ni * 16 + lane15;
                outp[(size_t)(b * 2048 + i) * 768 + h * 64 + dd] =
                    (__bf16)acc[mi][ni][r];
            }
}

// ---------------------------------------------------------------------------
// N5: out = out_pre @ Wp^T + bp  (f32)
// ---------------------------------------------------------------------------
__global__ __launch_bounds__(256, 2)
void k_out(const __bf16* __restrict__ out_pre, const __bf16* __restrict__ Wpb,
           const float* __restrict__ bp, float* __restrict__ out)
{
    __shared__ __attribute__((aligned(16))) char smem[98304];
    const int bid = blockIdx.x;
    gemm_phase<128, 1>(smem, out_pre, Wpb, out, bp, 768, 768, 768, 768,
                       (bid / 6) * 128, (bid % 6) * 128);
}

// ---------------------------------------------------------------------------
extern "C" void kernel_launch(void* const* d_in, const int* in_sizes, int n_in,
                              void* d_out, int out_size, void* d_ws, size_t ws_size,
                              hipStream_t stream)
{
    (void)in_sizes; (void)n_in; (void)out_size; (void)ws_size;
    const float* x  = (const float*)d_in[0];
    const float* Wq = (const float*)d_in[1];
    const float* Wk = (const float*)d_in[2];
    const float* Wv = (const float*)d_in[3];
    const float* Wp = (const float*)d_in[4];
    const float* bp = (const float*)d_in[5];

    char* w = (char*)d_ws;
    auto alloc = [&](size_t bytes) {
        char* p = w; w += (bytes + 255) & ~(size_t)255; return p;
    };
    float*  x_part  = (float*) alloc((size_t)64 * 768 * 4);
    __bf16* xb      = (__bf16*)alloc((size_t)4096 * 768 * 2);
    __bf16* Wvb     = (__bf16*)alloc((size_t)768 * 768 * 2);
    __bf16* Wpb     = (__bf16*)alloc((size_t)768 * 768 * 2);
    __bf16* Ub      = (__bf16*)alloc((size_t)32 * 768 * 2);
    float*  z_t     = (float*) alloc((size_t)24 * 2048 * 4);
    __bf16* VT      = (__bf16*)alloc((size_t)768 * 4096 * 2);
    __bf16* out_pre = (__bf16*)alloc((size_t)4096 * 768 * 2);

    k_prep<<<512, 256, 0, stream>>>(x, Wv, Wp, xb, Wvb, Wpb, x_part);
    k_ub  <<<96,  256, 0, stream>>>(x_part, Wk, Wq, Ub);
    k_mid <<<224, 256, 0, stream>>>(xb, Wvb, Ub, VT, z_t);
    k_conv<<<384, 256, 0, stream>>>(z_t, VT, out_pre);
    k_out <<<192, 256, 0, stream>>>(out_pre, Wpb, bp, (float*)d_out);
}